// Round 4
// baseline (527.420 us; speedup 1.0000x reference)
//
#include <hip/hip_runtime.h>
#include <math.h>

// CurvatureLoss: brute-force KNN + curvature gathers + scalar loss.
// B=2, N=8192, [B,N,3] fp32. L2-resident; VALU-instruction-bound.
// Two-phase KNN: phase A (first 1024 pts) exact insert-scan -> threshold T =
// 10th-best-so-far; phase B filters remaining 7168 pts with d<=T (superset of
// final top-K members), appending rare hits to an LDS buffer; final lex-select.

constexpr int TILE  = 512;   // ref points staged per LDS tile
constexpr int BLOCK = 256;
constexpr int PA_PTS = 1024; // phase-A candidates (2 tiles)
constexpr float RADIUS2 = 2.5f;

__device__ __forceinline__ float sq3(float x, float y, float z) {
    return fmaf(x, x, fmaf(y, y, z * z));
}
// stable ordering (matches jax.lax.top_k tie-break)
__device__ __forceinline__ bool lex_less(float d1, int i1, float d2, int i2) {
    return (d1 < d2) || (d1 == d2 && i1 < i2);
}

// KIND 0: fused curvature passes (mode from blockIdx):
//   mode 0: q=ref=gather=tgt           -> outA (curv2)
//   mode 1: q=ref=src, gather=src+flow -> outB (moved)
// KIND 1: interp+loss: q=src+flow, ref=tgt, gather curv2, subtract moved -> outA
template <int K, int CPQ, int KIND, int CAP>
__global__ __launch_bounds__(BLOCK)
void knn_kernel(const float* __restrict__ src,
                const float* __restrict__ tgt,
                const float* __restrict__ flow,
                const float* __restrict__ curv2,
                const float* __restrict__ moved,
                float* __restrict__ outA,
                float* __restrict__ outB,
                int N, float invB)
{
    constexpr int QPB = BLOCK / CPQ;  // queries per block
    __shared__ float4 spt[TILE];
    __shared__ float  smd[QPB][CPQ][K];
    __shared__ int    smi[QPB][CPQ][K];
    __shared__ float  hd[QPB][CAP];   // phase-B hit distances
    __shared__ int    hx[QPB][CAP];   // phase-B hit indices
    __shared__ int    hcnt[QPB];
    __shared__ float  Tsh[QPB];
    __shared__ float  lsum;

    const int tid = threadIdx.x;
    const int ql  = tid / CPQ;        // query within block
    const int c   = tid % CPQ;        // chunk lane within query
    const int bpb = N / QPB;

    int blk = blockIdx.x;
    int mode = 0;
    if (KIND == 0) {
        const int half = gridDim.x >> 1;
        mode = (blk >= half);
        blk -= mode ? half : 0;
    }
    const int b  = blk / bpb;
    const int qi = (blk % bpb) * QPB + ql;
    const size_t bbase = (size_t)b * N * 3;

    const float* qb;    // query-point base (also ref for self-KNN)
    const float* refb;  // scan reference base
    const float* addf;  // flow base
    if (KIND == 0) {
        qb   = (mode == 0 ? tgt : src) + bbase;
        refb = qb;
        addf = (mode == 0) ? nullptr : flow + bbase;
    } else {
        qb   = src + bbase;
        refb = tgt + bbase;
        addf = flow + bbase;
    }

    float qx = qb[(size_t)qi * 3 + 0];
    float qy = qb[(size_t)qi * 3 + 1];
    float qz = qb[(size_t)qi * 3 + 2];
    if (KIND == 1) {   // query = warped = src + flow
        qx += addf[(size_t)qi * 3 + 0];
        qy += addf[(size_t)qi * 3 + 1];
        qz += addf[(size_t)qi * 3 + 2];
    }
    const float qq  = sq3(qx, qy, qz);
    const float m2x = -2.0f * qx, m2y = -2.0f * qy, m2z = -2.0f * qz;

    // ---------------- Phase A: exact insert-scan of first PA_PTS ----------------
    float bd[K]; int bi[K];
#pragma unroll
    for (int k = 0; k < K; ++k) { bd[k] = INFINITY; bi[k] = 0x7FFFFFFF; }
    float gd = INFINITY;

    for (int t0 = 0; t0 < PA_PTS; t0 += TILE) {
        __syncthreads();
        for (int j = tid; j < TILE; j += BLOCK) {
            float x = refb[(size_t)(t0 + j) * 3 + 0];
            float y = refb[(size_t)(t0 + j) * 3 + 1];
            float z = refb[(size_t)(t0 + j) * 3 + 2];
            spt[j] = make_float4(x, y, z, sq3(x, y, z));
        }
        __syncthreads();

        for (int i0 = 0; i0 < TILE / CPQ; i0 += 16) {
            {   // refresh gate: min of current worsts across this query's lanes
                float m = bd[K - 1];
#pragma unroll
                for (int s = 1; s < CPQ; s <<= 1)
                    m = fminf(m, __shfl_xor(m, s, CPQ));
                gd = m;
            }
#pragma unroll
            for (int ii = 0; ii < 16; ++ii) {
                const int j = (i0 + ii) * CPQ + c;
                float4 p = spt[j];
                float d = fmaf(m2x, p.x, fmaf(m2y, p.y, fmaf(m2z, p.z, qq + p.w)));
                bool pass = d < gd;
                if (__any(pass)) {
                    if (pass) {
                        bd[K - 1] = d; bi[K - 1] = t0 + j;
#pragma unroll
                        for (int p2 = K - 1; p2 > 0; --p2) {
                            if (bd[p2] < bd[p2 - 1]) {
                                float td = bd[p2]; bd[p2] = bd[p2 - 1]; bd[p2 - 1] = td;
                                int ti = bi[p2];  bi[p2] = bi[p2 - 1]; bi[p2 - 1] = ti;
                            }
                        }
                        gd = fminf(gd, bd[K - 1]);
                    }
                }
            }
        }
    }

#pragma unroll
    for (int k = 0; k < K; ++k) { smd[ql][c][k] = bd[k]; smi[ql][c][k] = bi[k]; }
    if (c == 0) hcnt[ql] = 0;
    if (KIND == 1 && tid == 0) lsum = 0.0f;
    __syncthreads();

    // merge phase-A per-lane lists -> exact top-K of first PA_PTS; T = K-th best
    float fd[K]; int fi[K];
    if (c == 0) {
        int pp[CPQ];
#pragma unroll
        for (int cc = 0; cc < CPQ; ++cc) pp[cc] = 0;
#pragma unroll
        for (int k = 0; k < K; ++k) {
            float bdm = INFINITY; int bim = 0x7FFFFFFF; int bc = -1;
#pragma unroll
            for (int cc = 0; cc < CPQ; ++cc) {
                float dd = smd[ql][cc][pp[cc]];
                int   ii = smi[ql][cc][pp[cc]];
                if (lex_less(dd, ii, bdm, bim)) { bdm = dd; bim = ii; bc = cc; }
            }
            fd[k] = bdm; fi[k] = bim;
#pragma unroll
            for (int cc = 0; cc < CPQ; ++cc) pp[cc] += (bc == cc);
        }
        Tsh[ql] = fd[K - 1];
    }
    __syncthreads();
    const float T = Tsh[ql];

    // ---------------- Phase B: filter remaining points against T ----------------
    for (int t0 = PA_PTS; t0 < N; t0 += TILE) {
        __syncthreads();
        for (int j = tid; j < TILE; j += BLOCK) {
            float x = refb[(size_t)(t0 + j) * 3 + 0];
            float y = refb[(size_t)(t0 + j) * 3 + 1];
            float z = refb[(size_t)(t0 + j) * 3 + 2];
            spt[j] = make_float4(x, y, z, sq3(x, y, z));
        }
        __syncthreads();
#pragma unroll 4
        for (int i = 0; i < TILE / CPQ; ++i) {
            const int j = i * CPQ + c;
            float4 p = spt[j];
            float d = fmaf(m2x, p.x, fmaf(m2y, p.y, fmaf(m2z, p.z, qq + p.w)));
            if (d <= T) {   // superset of all possible final top-K members
                int slot = atomicAdd(&hcnt[ql], 1);
                if (slot < CAP) { hd[ql][slot] = d; hx[ql][slot] = t0 + j; }
            }
        }
    }
    __syncthreads();

    // ---------------- Final select + epilogue (c==0 per query) ----------------
    if (c == 0) {
        const int cnt = min(hcnt[ql], CAP);
        for (int h = 0; h < cnt; ++h) {
            float d = hd[ql][h]; int ii = hx[ql][h];
            if (lex_less(d, ii, fd[K - 1], fi[K - 1])) {
                fd[K - 1] = d; fi[K - 1] = ii;
#pragma unroll
                for (int p2 = K - 1; p2 > 0; --p2) {
                    if (lex_less(fd[p2], fi[p2], fd[p2 - 1], fi[p2 - 1])) {
                        float td = fd[p2]; fd[p2] = fd[p2 - 1]; fd[p2 - 1] = td;
                        int ti = fi[p2];  fi[p2] = fi[p2 - 1]; fi[p2 - 1] = ti;
                    }
                }
            }
        }

        if (KIND == 0) {
            float cx = qx, cy = qy, cz = qz;
            if (mode == 1) {
                cx += addf[(size_t)qi * 3 + 0];
                cy += addf[(size_t)qi * 3 + 1];
                cz += addf[(size_t)qi * 3 + 2];
            }
            float gx = 0.f, gy = 0.f, gz = 0.f;
#pragma unroll
            for (int k = 0; k < K; ++k) {
                int j = (fd[k] > RADIUS2) ? fi[0] : fi[k];
                float px = refb[(size_t)j * 3 + 0];
                float py = refb[(size_t)j * 3 + 1];
                float pz = refb[(size_t)j * 3 + 2];
                if (mode == 1) {
                    px += addf[(size_t)j * 3 + 0];
                    py += addf[(size_t)j * 3 + 1];
                    pz += addf[(size_t)j * 3 + 2];
                }
                gx += px - cx; gy += py - cy; gz += pz - cz;
            }
            float* outp = (mode == 0) ? outA : outB;
            outp[bbase + (size_t)qi * 3 + 0] = gx / 9.0f;
            outp[bbase + (size_t)qi * 3 + 1] = gy / 9.0f;
            outp[bbase + (size_t)qi * 3 + 2] = gz / 9.0f;
        } else {
            float w[K]; float wsum = 0.f;
#pragma unroll
            for (int k = 0; k < K; ++k) { w[k] = 1.0f / (fd[k] + 1e-8f); wsum += w[k]; }
            float ix = 0.f, iy = 0.f, iz = 0.f;
#pragma unroll
            for (int k = 0; k < K; ++k) {
                int j = (fd[k] > RADIUS2) ? fi[0] : fi[k];
                float wn = w[k] / wsum;
                ix += wn * curv2[bbase + (size_t)j * 3 + 0];
                iy += wn * curv2[bbase + (size_t)j * 3 + 1];
                iz += wn * curv2[bbase + (size_t)j * 3 + 2];
            }
            float dx = ix - moved[bbase + (size_t)qi * 3 + 0];
            float dy = iy - moved[bbase + (size_t)qi * 3 + 1];
            float dz = iz - moved[bbase + (size_t)qi * 3 + 2];
            float sqv = fmaf(dx, dx, fmaf(dy, dy, dz * dz));
            atomicAdd(&lsum, sqv);
        }
    }

    if (KIND == 1) {
        __syncthreads();
        if (tid == 0) atomicAdd(outA, lsum * invB);
    }
}

extern "C" void kernel_launch(void* const* d_in, const int* in_sizes, int n_in,
                              void* d_out, int out_size, void* d_ws, size_t ws_size,
                              hipStream_t stream) {
    const float* src  = (const float*)d_in[0];  // pc_source [B,N,3]
    const float* tgt  = (const float*)d_in[1];  // pc_target [B,N,3]
    const float* flow = (const float*)d_in[2];  // pred_flow [B,N,3]
    float* out = (float*)d_out;

    const int B = 2;
    const int N = in_sizes[0] / (B * 3);        // 8192

    float* curv2 = (float*)d_ws;                // [B,N,3]
    float* moved = curv2 + (size_t)B * N * 3;   // [B,N,3]

    hipMemsetAsync(d_out, 0, sizeof(float), stream);

    // fused: curv2 = curvature(tgt); moved = curvature(src, src+flow)
    // K=10, CPQ=8, QPB=32, CAP=192 (expected ~80 hits/query)
    knn_kernel<10, 8, 0, 192><<<2 * B * (N / 32), BLOCK, 0, stream>>>(
        src, tgt, flow, nullptr, nullptr, curv2, moved, N, 0.f);

    // interp + loss: K=5, CPQ=16, QPB=16, CAP=128 (expected ~40 hits/query)
    knn_kernel<5, 16, 1, 128><<<B * (N / 16), BLOCK, 0, stream>>>(
        src, tgt, flow, curv2, moved, out, nullptr, N, 1.0f / B);
}

// Round 5
// 321.342 us; speedup vs baseline: 1.6413x; 1.6413x over previous
//
#include <hip/hip_runtime.h>
#include <math.h>

// CurvatureLoss: brute-force KNN + curvature gathers + scalar loss.
// B=2, N=8192, [B,N,3] fp32. L2-resident. Two-phase filter KNN:
// phase A (1024-pt prefix) exact insert-scan -> per-query threshold T;
// phase B filters remaining points (d<=T superset), LDS hit buffer;
// parallel final select. Double-buffered tiles, one barrier per tile.

constexpr int TILE   = 256;  // ref points per LDS tile (== BLOCK: 1 pt/thread staging)
constexpr int BLOCK  = 256;
constexpr int PA_PTS = 1024; // phase-A prefix
constexpr float RADIUS2 = 2.5f;

__device__ __forceinline__ float sq3(float x, float y, float z) {
    return fmaf(x, x, fmaf(y, y, z * z));
}
// stable ordering (matches jax.lax.top_k tie-break)
__device__ __forceinline__ bool lex_less(float d1, int i1, float d2, int i2) {
    return (d1 < d2) || (d1 == d2 && i1 < i2);
}

// KIND 0: fused curvature passes (mode from blockIdx):
//   mode 0: q=ref=gather=tgt           -> outA (curv2)
//   mode 1: q=ref=src, gather=src+flow -> outB (moved)
// KIND 1: interp+loss: q=src+flow, ref=tgt, gather curv2, subtract moved -> outA
template <int K, int CPQ, int KIND, int CAP>
__global__ __launch_bounds__(BLOCK)
void knn_kernel(const float* __restrict__ src,
                const float* __restrict__ tgt,
                const float* __restrict__ flow,
                const float* __restrict__ curv2,
                const float* __restrict__ moved,
                float* __restrict__ outA,
                float* __restrict__ outB,
                int N, float invB)
{
    constexpr int QPB = BLOCK / CPQ;  // queries per block (16)
    // pool_d/pool_i alias two disjoint-lifetime uses:
    //   (a) per-lane phase-A / final sorted lists: [QPB*CPQ*K]
    //   (b) hit buffer: [QPB*CAP]
    constexpr int PAIRS = (QPB * CPQ * K > QPB * CAP) ? QPB * CPQ * K : QPB * CAP;
    __shared__ float4 spt[2][TILE];     // double-buffered point tiles
    __shared__ float  pool_d[PAIRS];
    __shared__ int    pool_i[PAIRS];
    __shared__ int    hcnt[QPB];
    __shared__ float  Tsh[QPB];
    __shared__ float  lsum;

    const int tid = threadIdx.x;
    const int ql  = tid / CPQ;        // query within block
    const int c   = tid % CPQ;        // chunk lane within query
    const int bpb = N / QPB;

    int blk = blockIdx.x;
    int mode = 0;
    if (KIND == 0) {
        const int half = gridDim.x >> 1;
        mode = (blk >= half);
        blk -= mode ? half : 0;
    }
    const int b  = blk / bpb;
    const int qi = (blk % bpb) * QPB + ql;
    const size_t bbase = (size_t)b * N * 3;

    const float* qb;    // query-point base (also ref for self-KNN)
    const float* refb;  // scan reference base
    const float* addf;  // flow base
    if (KIND == 0) {
        qb   = (mode == 0 ? tgt : src) + bbase;
        refb = qb;
        addf = (mode == 0) ? nullptr : flow + bbase;
    } else {
        qb   = src + bbase;
        refb = tgt + bbase;
        addf = flow + bbase;
    }

    float qx = qb[(size_t)qi * 3 + 0];
    float qy = qb[(size_t)qi * 3 + 1];
    float qz = qb[(size_t)qi * 3 + 2];
    if (KIND == 1) {   // query = warped = src + flow
        qx += addf[(size_t)qi * 3 + 0];
        qy += addf[(size_t)qi * 3 + 1];
        qz += addf[(size_t)qi * 3 + 2];
    }
    const float qq  = sq3(qx, qy, qz);
    const float m2x = -2.0f * qx, m2y = -2.0f * qy, m2z = -2.0f * qz;

    float rx, ry, rz;   // staging prefetch registers (1 point/thread)

    // ---------------- Phase A: exact insert-scan of PA_PTS prefix ----------------
    float bd[K]; int bi[K];
#pragma unroll
    for (int k = 0; k < K; ++k) { bd[k] = INFINITY; bi[k] = 0x7FFFFFFF; }
    float gd = INFINITY;

    {   // prime tile 0
        size_t o = (size_t)tid * 3;
        rx = refb[o]; ry = refb[o + 1]; rz = refb[o + 2];
    }
    spt[0][tid] = make_float4(rx, ry, rz, sq3(rx, ry, rz));
    __syncthreads();

    constexpr int PA_T = PA_PTS / TILE;
    for (int t = 0; t < PA_T; ++t) {
        if (t + 1 < PA_T) {
            size_t o = (size_t)(t + 1) * TILE * 3 + (size_t)tid * 3;
            rx = refb[o]; ry = refb[o + 1]; rz = refb[o + 2];
        }
        const float4* sp = spt[t & 1];
        {   // refresh gate: min of current worsts across this query's lanes
            float m = bd[K - 1];
#pragma unroll
            for (int s = 1; s < CPQ; s <<= 1)
                m = fminf(m, __shfl_xor(m, s, CPQ));
            gd = m;
        }
#pragma unroll
        for (int i = 0; i < TILE / CPQ; ++i) {
            const int j = i * CPQ + c;
            float4 p = sp[j];
            float d = fmaf(m2x, p.x, fmaf(m2y, p.y, fmaf(m2z, p.z, qq + p.w)));
            bool pass = d < gd;
            if (__any(pass)) {          // wave-uniform branch
                if (pass) {
                    bd[K - 1] = d; bi[K - 1] = t * TILE + j;
#pragma unroll
                    for (int p2 = K - 1; p2 > 0; --p2) {
                        if (bd[p2] < bd[p2 - 1]) {
                            float td = bd[p2]; bd[p2] = bd[p2 - 1]; bd[p2 - 1] = td;
                            int ti = bi[p2];  bi[p2] = bi[p2 - 1]; bi[p2 - 1] = ti;
                        }
                    }
                    gd = fminf(gd, bd[K - 1]);
                }
            }
        }
        if (t + 1 < PA_T)
            spt[(t + 1) & 1][tid] = make_float4(rx, ry, rz, sq3(rx, ry, rz));
        __syncthreads();
    }

    // store per-lane sorted lists into pool (role a)
#pragma unroll
    for (int k = 0; k < K; ++k) {
        pool_d[(ql * CPQ + c) * K + k] = bd[k];
        pool_i[(ql * CPQ + c) * K + k] = bi[k];
    }
    if (KIND == 1 && tid == 0) lsum = 0.0f;
    // prefetch first phase-B tile now: latency hides under the merge
    {
        size_t o = (size_t)PA_PTS * 3 + (size_t)tid * 3;
        rx = refb[o]; ry = refb[o + 1]; rz = refb[o + 2];
    }
    __syncthreads();

    // merge phase-A lists (c==0): exact top-K of prefix; T = K-th best
    float fd[K]; int fi[K];
    if (c == 0) {
        int pp[CPQ];
#pragma unroll
        for (int cc = 0; cc < CPQ; ++cc) pp[cc] = 0;
#pragma unroll
        for (int k = 0; k < K; ++k) {
            float bdm = INFINITY; int bim = 0x7FFFFFFF; int bc = -1;
#pragma unroll
            for (int cc = 0; cc < CPQ; ++cc) {
                float dd = pool_d[(ql * CPQ + cc) * K + pp[cc]];
                int   ii = pool_i[(ql * CPQ + cc) * K + pp[cc]];
                if (lex_less(dd, ii, bdm, bim)) { bdm = dd; bim = ii; bc = cc; }
            }
            fd[k] = bdm; fi[k] = bim;
#pragma unroll
            for (int cc = 0; cc < CPQ; ++cc) pp[cc] += (bc == cc);
        }
        Tsh[ql] = fd[K - 1];
    }
    __syncthreads();   // merges done reading pool; Tsh visible

    // seed hit buffer (pool role b) with phase-A top-K; stage first B tile
    if (c == 0) {
#pragma unroll
        for (int k = 0; k < K; ++k) {
            pool_d[ql * CAP + k] = fd[k];
            pool_i[ql * CAP + k] = fi[k];
        }
        hcnt[ql] = K;
    }
    const float T = Tsh[ql];
    spt[0][tid] = make_float4(rx, ry, rz, sq3(rx, ry, rz));
    __syncthreads();

    // ---------------- Phase B: filter remaining points against T ----------------
    const int nbt = (N - PA_PTS) / TILE;
    for (int t = 0; t < nbt; ++t) {
        if (t + 1 < nbt) {
            size_t o = (size_t)(PA_PTS + (t + 1) * TILE) * 3 + (size_t)tid * 3;
            rx = refb[o]; ry = refb[o + 1]; rz = refb[o + 2];
        }
        const float4* sp = spt[t & 1];
#pragma unroll
        for (int i = 0; i < TILE / CPQ; ++i) {
            const int j = i * CPQ + c;
            float4 p = sp[j];
            float d = fmaf(m2x, p.x, fmaf(m2y, p.y, fmaf(m2z, p.z, qq + p.w)));
            bool hit = d <= T;   // superset of final top-K members
            if (__any(hit)) {
                if (hit) {
                    int slot = atomicAdd(&hcnt[ql], 1);
                    if (slot < CAP) {
                        pool_d[ql * CAP + slot] = d;
                        pool_i[ql * CAP + slot] = PA_PTS + t * TILE + j;
                    }
                }
            }
        }
        if (t + 1 < nbt)
            spt[(t + 1) & 1][tid] = make_float4(rx, ry, rz, sq3(rx, ry, rz));
        __syncthreads();
    }

    // ---------------- Final select: parallel slice-insert + merge ----------------
    const int cnt = min(hcnt[ql], CAP);
    float nd[K]; int ni[K];
#pragma unroll
    for (int k = 0; k < K; ++k) { nd[k] = INFINITY; ni[k] = 0x7FFFFFFF; }
    for (int h = c; h < cnt; h += CPQ) {
        float d  = pool_d[ql * CAP + h];
        int   ii = pool_i[ql * CAP + h];
        if (lex_less(d, ii, nd[K - 1], ni[K - 1])) {
            nd[K - 1] = d; ni[K - 1] = ii;
#pragma unroll
            for (int p2 = K - 1; p2 > 0; --p2) {
                if (lex_less(nd[p2], ni[p2], nd[p2 - 1], ni[p2 - 1])) {
                    float td = nd[p2]; nd[p2] = nd[p2 - 1]; nd[p2 - 1] = td;
                    int ti = ni[p2];  ni[p2] = ni[p2 - 1]; ni[p2 - 1] = ti;
                }
            }
        }
    }
    __syncthreads();   // hit buffer consumed; pool reusable (role a)
#pragma unroll
    for (int k = 0; k < K; ++k) {
        pool_d[(ql * CPQ + c) * K + k] = nd[k];
        pool_i[(ql * CPQ + c) * K + k] = ni[k];
    }
    __syncthreads();

    if (c == 0) {
        int pp[CPQ];
#pragma unroll
        for (int cc = 0; cc < CPQ; ++cc) pp[cc] = 0;
#pragma unroll
        for (int k = 0; k < K; ++k) {
            float bdm = INFINITY; int bim = 0x7FFFFFFF; int bc = -1;
#pragma unroll
            for (int cc = 0; cc < CPQ; ++cc) {
                float dd = pool_d[(ql * CPQ + cc) * K + pp[cc]];
                int   ii = pool_i[(ql * CPQ + cc) * K + pp[cc]];
                if (lex_less(dd, ii, bdm, bim)) { bdm = dd; bim = ii; bc = cc; }
            }
            fd[k] = bdm; fi[k] = bim;
#pragma unroll
            for (int cc = 0; cc < CPQ; ++cc) pp[cc] += (bc == cc);
        }

        if (KIND == 0) {
            float cx = qx, cy = qy, cz = qz;
            if (mode == 1) {
                cx += addf[(size_t)qi * 3 + 0];
                cy += addf[(size_t)qi * 3 + 1];
                cz += addf[(size_t)qi * 3 + 2];
            }
            float gx = 0.f, gy = 0.f, gz = 0.f;
#pragma unroll
            for (int k = 0; k < K; ++k) {
                int j = (fd[k] > RADIUS2) ? fi[0] : fi[k];
                float px = refb[(size_t)j * 3 + 0];
                float py = refb[(size_t)j * 3 + 1];
                float pz = refb[(size_t)j * 3 + 2];
                if (mode == 1) {
                    px += addf[(size_t)j * 3 + 0];
                    py += addf[(size_t)j * 3 + 1];
                    pz += addf[(size_t)j * 3 + 2];
                }
                gx += px - cx; gy += py - cy; gz += pz - cz;
            }
            float* outp = (mode == 0) ? outA : outB;
            outp[bbase + (size_t)qi * 3 + 0] = gx / 9.0f;
            outp[bbase + (size_t)qi * 3 + 1] = gy / 9.0f;
            outp[bbase + (size_t)qi * 3 + 2] = gz / 9.0f;
        } else {
            float w[K]; float wsum = 0.f;
#pragma unroll
            for (int k = 0; k < K; ++k) { w[k] = 1.0f / (fd[k] + 1e-8f); wsum += w[k]; }
            float ix = 0.f, iy = 0.f, iz = 0.f;
#pragma unroll
            for (int k = 0; k < K; ++k) {
                int j = (fd[k] > RADIUS2) ? fi[0] : fi[k];
                float wn = w[k] / wsum;
                ix += wn * curv2[bbase + (size_t)j * 3 + 0];
                iy += wn * curv2[bbase + (size_t)j * 3 + 1];
                iz += wn * curv2[bbase + (size_t)j * 3 + 2];
            }
            float dx = ix - moved[bbase + (size_t)qi * 3 + 0];
            float dy = iy - moved[bbase + (size_t)qi * 3 + 1];
            float dz = iz - moved[bbase + (size_t)qi * 3 + 2];
            float sqv = fmaf(dx, dx, fmaf(dy, dy, dz * dz));
            atomicAdd(&lsum, sqv);
        }
    }

    if (KIND == 1) {
        __syncthreads();
        if (tid == 0) atomicAdd(outA, lsum * invB);
    }
}

extern "C" void kernel_launch(void* const* d_in, const int* in_sizes, int n_in,
                              void* d_out, int out_size, void* d_ws, size_t ws_size,
                              hipStream_t stream) {
    const float* src  = (const float*)d_in[0];  // pc_source [B,N,3]
    const float* tgt  = (const float*)d_in[1];  // pc_target [B,N,3]
    const float* flow = (const float*)d_in[2];  // pred_flow [B,N,3]
    float* out = (float*)d_out;

    const int B = 2;
    const int N = in_sizes[0] / (B * 3);        // 8192

    float* curv2 = (float*)d_ws;                // [B,N,3]
    float* moved = curv2 + (size_t)B * N * 3;   // [B,N,3]

    hipMemsetAsync(d_out, 0, sizeof(float), stream);

    // fused: curv2 = curvature(tgt); moved = curvature(src, src+flow)
    // K=10, CPQ=16, QPB=16, CAP=192: grid = 2 modes * B * N/16 = 2048 blocks
    knn_kernel<10, 16, 0, 192><<<2 * B * (N / 16), BLOCK, 0, stream>>>(
        src, tgt, flow, nullptr, nullptr, curv2, moved, N, 0.f);

    // interp + loss: K=5, CPQ=16, QPB=16, CAP=128: grid = 1024 blocks
    knn_kernel<5, 16, 1, 128><<<B * (N / 16), BLOCK, 0, stream>>>(
        src, tgt, flow, curv2, moved, out, nullptr, N, 1.0f / B);
}

// Round 6
// 320.062 us; speedup vs baseline: 1.6479x; 1.0040x over previous
//
#include <hip/hip_runtime.h>
#include <math.h>

// CurvatureLoss via x-sorted window-pruned exact KNN.
// B=2, N=8192, [B,N,3] fp32, points ~ N(0,1).
// Setup: bucket-sort each set {tgt, src, warped} by x (monotone clamped buckets).
// KNN: phase A = exact insert-scan of the 1024 sorted points around the block's
// 32 consecutive queries -> tight per-query threshold T; phase B = filter only
// the residual x-window slivers outside the phase-A window (d<=T superset);
// exact (d, orig_idx) lex select => deterministic despite scatter order.

constexpr int BLOCK = 256;
constexpr int TILE  = 256;
constexpr int NB    = 256;   // x-buckets
constexpr float XLO = -6.0f, XHI = 6.0f;
constexpr float BKS = NB / (XHI - XLO);
constexpr int WPTS  = 1024;  // phase-A window (4 tiles)
constexpr float RADIUS2 = 2.5f;

__device__ __forceinline__ float sq3(float x, float y, float z) {
    return fmaf(x, x, fmaf(y, y, z * z));
}
__device__ __forceinline__ bool lex_less(float d1, int i1, float d2, int i2) {
    return (d1 < d2) || (d1 == d2 && i1 < i2);
}
// monotone non-decreasing in x even with clamping -> window logic stays exact
__device__ __forceinline__ int bkt_of(float x) {
    int k = (int)((x - XLO) * BKS);
    return k < 0 ? 0 : (k > NB - 1 ? NB - 1 : k);
}

// Bucket-sort one (set,b): set 0=tgt, 1=src, 2=warped(src+flow). grid = 6 blocks.
__global__ __launch_bounds__(BLOCK)
void sort_kernel(const float* __restrict__ src, const float* __restrict__ tgt,
                 const float* __restrict__ flow,
                 float4* __restrict__ xyzw, int* __restrict__ sidx,
                 int* __restrict__ bstart, int N)
{
    const int set = blockIdx.x >> 1;
    const int b   = blockIdx.x & 1;
    const size_t pbase = (size_t)b * N * 3;
    const float* P = (set == 0) ? tgt : src;
    const bool addF = (set == 2);
    float4* oxy = xyzw + (size_t)blockIdx.x * N;
    int*    osx = sidx + (size_t)blockIdx.x * N;
    int*    obs = bstart + (size_t)blockIdx.x * (NB + 1);

    __shared__ int hist[NB];
    __shared__ int bs[NB + 1];
    for (int k = threadIdx.x; k < NB; k += BLOCK) hist[k] = 0;
    __syncthreads();
    for (int i = threadIdx.x; i < N; i += BLOCK) {
        float x = P[pbase + (size_t)i * 3];
        if (addF) x += flow[pbase + (size_t)i * 3];
        atomicAdd(&hist[bkt_of(x)], 1);
    }
    __syncthreads();
    if (threadIdx.x == 0) {
        int run = 0;
        for (int k = 0; k < NB; ++k) { bs[k] = run; run += hist[k]; }
        bs[NB] = run;
    }
    __syncthreads();
    for (int k = threadIdx.x; k <= NB; k += BLOCK) obs[k] = bs[k];
    for (int k = threadIdx.x; k < NB; k += BLOCK) hist[k] = bs[k];  // cursors
    __syncthreads();
    for (int i = threadIdx.x; i < N; i += BLOCK) {
        size_t o = pbase + (size_t)i * 3;
        float x = P[o], y = P[o + 1], z = P[o + 2];
        if (addF) { x += flow[o]; y += flow[o + 1]; z += flow[o + 2]; }
        int pos = atomicAdd(&hist[bkt_of(x)], 1);
        oxy[pos] = make_float4(x, y, z, sq3(x, y, z));
        osx[pos] = i;
    }
}

// KIND 0: self-KNN curvature (mode 0: tgt->curv2=outA; mode 1: src, gather warped ->moved=outB)
// KIND 1: warped->tgt KNN, interp curv2, subtract moved, loss -> outA
template <int K, int CPQ, int KIND, int CAP>
__global__ __launch_bounds__(BLOCK)
void knn_kernel(const float* __restrict__ src, const float* __restrict__ tgt,
                const float* __restrict__ flow,
                const float4* __restrict__ ws_xyzw, const int* __restrict__ ws_sidx,
                const int* __restrict__ ws_bs,
                const float* __restrict__ curv2, const float* __restrict__ moved,
                float* __restrict__ outA, float* __restrict__ outB,
                int N, float invB)
{
    constexpr int QPB = BLOCK / CPQ;   // 32 queries/block
    constexpr int PAIRS = (QPB * CPQ * K > QPB * CAP) ? QPB * CPQ * K : QPB * CAP;
    __shared__ float4 spt[TILE];
    __shared__ int    sid[TILE];
    __shared__ float  pool_d[PAIRS];
    __shared__ int    pool_i[PAIRS];
    __shared__ int    sbs[NB + 1];
    __shared__ int    hcnt[QPB];
    __shared__ float  Tsh[QPB];
    __shared__ int    uminS, umaxS;
    __shared__ float  lsum;

    const int tid = threadIdx.x;
    const int ql  = tid / CPQ;
    const int c   = tid % CPQ;
    const int bpb = N / QPB;

    int blk = blockIdx.x;
    int mode = 0;
    if (KIND == 0) { int half = gridDim.x >> 1; mode = (blk >= half); blk -= mode ? half : 0; }
    const int b  = blk / bpb;
    const int q0 = (blk % bpb) * QPB;
    const size_t bbase = (size_t)b * N * 3;

    const int qset = (KIND == 0) ? mode : 2;
    const int rset = (KIND == 0) ? mode : 0;
    const float4* sQ  = ws_xyzw + (size_t)(qset * 2 + b) * N;
    const int*    sQi = ws_sidx + (size_t)(qset * 2 + b) * N;
    const float4* sRf = ws_xyzw + (size_t)(rset * 2 + b) * N;
    const int*    sRi = ws_sidx + (size_t)(rset * 2 + b) * N;
    const int*    bsR = ws_bs   + (size_t)(rset * 2 + b) * (NB + 1);

    for (int k = tid; k <= NB; k += BLOCK) sbs[k] = bsR[k];

    // query (sorted order); output goes to orig index oqi
    const int qpos = q0 + ql;
    const float4 q4 = sQ[qpos];
    const int oqi = sQi[qpos];
    const float qx = q4.x, qy = q4.y, qz = q4.z, qq = q4.w;
    const float m2x = -2.0f * qx, m2y = -2.0f * qy, m2z = -2.0f * qz;

    // phase-A window (block-uniform, clamped)
    int wA0;
    if (KIND == 0) {
        wA0 = q0 + QPB / 2 - WPTS / 2;
    } else {
        float xm = sQ[q0 + QPB / 2].x;
        wA0 = bsR[bkt_of(xm)] - WPTS / 2;
    }
    wA0 = min(max(wA0, 0), N - WPTS);
    const int wA1 = wA0 + WPTS;

    // ---------------- Phase A: exact insert-scan of WPTS window ----------------
    float bd[K]; int bi[K];
#pragma unroll
    for (int k = 0; k < K; ++k) { bd[k] = INFINITY; bi[k] = 0x7FFFFFFF; }
    float gd = INFINITY;

    for (int t = 0; t < WPTS / TILE; ++t) {
        __syncthreads();
        spt[tid] = sRf[wA0 + t * TILE + tid];
        sid[tid] = sRi[wA0 + t * TILE + tid];
        __syncthreads();
        for (int i0 = 0; i0 < TILE / CPQ; i0 += 16) {
            {   // refresh gate: min of current worsts across this query's lanes
                float m = bd[K - 1];
#pragma unroll
                for (int s = 1; s < CPQ; s <<= 1)
                    m = fminf(m, __shfl_xor(m, s, CPQ));
                gd = m;
            }
#pragma unroll
            for (int ii = 0; ii < 16; ++ii) {
                const int j = (i0 + ii) * CPQ + c;
                float4 p = spt[j];
                float d = fmaf(m2x, p.x, fmaf(m2y, p.y, fmaf(m2z, p.z, qq + p.w)));
                bool pass = d < gd;
                if (__any(pass)) {
                    if (pass) {
                        bd[K - 1] = d; bi[K - 1] = sid[j];
#pragma unroll
                        for (int p2 = K - 1; p2 > 0; --p2) {
                            if (bd[p2] < bd[p2 - 1]) {
                                float td = bd[p2]; bd[p2] = bd[p2 - 1]; bd[p2 - 1] = td;
                                int ti = bi[p2];  bi[p2] = bi[p2 - 1]; bi[p2 - 1] = ti;
                            }
                        }
                        gd = fminf(gd, bd[K - 1]);
                    }
                }
            }
        }
    }
    __syncthreads();

    // store per-lane lists (pool role a)
#pragma unroll
    for (int k = 0; k < K; ++k) {
        pool_d[(ql * CPQ + c) * K + k] = bd[k];
        pool_i[(ql * CPQ + c) * K + k] = bi[k];
    }
    if (tid == 0) { uminS = wA0; umaxS = wA1; if (KIND == 1) lsum = 0.0f; }
    __syncthreads();

    // merge (c==0) -> exact window top-K, T, per-query sliver range
    float fd[K]; int fi[K];
    if (c == 0) {
        int pp[CPQ];
#pragma unroll
        for (int cc = 0; cc < CPQ; ++cc) pp[cc] = 0;
#pragma unroll
        for (int k = 0; k < K; ++k) {
            float bdm = INFINITY; int bim = 0x7FFFFFFF; int bc = -1;
#pragma unroll
            for (int cc = 0; cc < CPQ; ++cc) {
                float dd = pool_d[(ql * CPQ + cc) * K + pp[cc]];
                int   ii = pool_i[(ql * CPQ + cc) * K + pp[cc]];
                if (lex_less(dd, ii, bdm, bim)) { bdm = dd; bim = ii; bc = cc; }
            }
            fd[k] = bdm; fi[k] = bim;
#pragma unroll
            for (int cc = 0; cc < CPQ; ++cc) pp[cc] += (bc == cc);
        }
        Tsh[ql] = fd[K - 1];
        float s = sqrtf(fd[K - 1]);
        int lo = sbs[bkt_of(qx - s)];
        int hi = sbs[bkt_of(qx + s) + 1];
        atomicMin(&uminS, lo);
        atomicMax(&umaxS, hi);
    }
    __syncthreads();   // pool role-a reads done

    if (c == 0) {      // seed hit buffer (pool role b)
#pragma unroll
        for (int k = 0; k < K; ++k) {
            pool_d[ql * CAP + k] = fd[k];
            pool_i[ql * CAP + k] = fi[k];
        }
        hcnt[ql] = K;
    }
    const float T = Tsh[ql];
    const int umin = uminS, umax = umaxS;
    __syncthreads();

    // -------- Phase B: filter the two slivers outside the phase-A window --------
    const int sL = min(umin, wA0), cL = wA0 - sL;
    const int sRg = wA1,           cR = max(umax, wA1) - wA1;
    for (int seg = 0; seg < 2; ++seg) {
        const int segS = seg ? sRg : sL;
        const int segC = seg ? cR  : cL;
        for (int t0 = 0; t0 < segC; t0 += TILE) {
            int ap = segS + t0 + tid;
            spt[tid] = (ap < segS + segC) ? sRf[ap]
                                          : make_float4(0.f, 0.f, 0.f, INFINITY);
            __syncthreads();
            for (int i = 0; i < TILE / CPQ; ++i) {
                const int j = i * CPQ + c;
                float4 p = spt[j];
                float d = fmaf(m2x, p.x, fmaf(m2y, p.y, fmaf(m2z, p.z, qq + p.w)));
                bool hit = d <= T;   // superset of final top-K members
                if (__any(hit)) {
                    if (hit) {
                        int slot = atomicAdd(&hcnt[ql], 1);
                        if (slot < CAP) {
                            pool_d[ql * CAP + slot] = d;
                            pool_i[ql * CAP + slot] = sRi[segS + t0 + j];
                        }
                    }
                }
            }
            __syncthreads();
        }
    }

    // ---------------- Final select: parallel slice-insert + merge ----------------
    const int cnt = min(hcnt[ql], CAP);
    float nd[K]; int ni[K];
#pragma unroll
    for (int k = 0; k < K; ++k) { nd[k] = INFINITY; ni[k] = 0x7FFFFFFF; }
    for (int h = c; h < cnt; h += CPQ) {
        float d  = pool_d[ql * CAP + h];
        int   ii = pool_i[ql * CAP + h];
        if (lex_less(d, ii, nd[K - 1], ni[K - 1])) {
            nd[K - 1] = d; ni[K - 1] = ii;
#pragma unroll
            for (int p2 = K - 1; p2 > 0; --p2) {
                if (lex_less(nd[p2], ni[p2], nd[p2 - 1], ni[p2 - 1])) {
                    float td = nd[p2]; nd[p2] = nd[p2 - 1]; nd[p2 - 1] = td;
                    int ti = ni[p2];  ni[p2] = ni[p2 - 1]; ni[p2 - 1] = ti;
                }
            }
        }
    }
    __syncthreads();
#pragma unroll
    for (int k = 0; k < K; ++k) {
        pool_d[(ql * CPQ + c) * K + k] = nd[k];
        pool_i[(ql * CPQ + c) * K + k] = ni[k];
    }
    __syncthreads();

    if (c == 0) {
        int pp[CPQ];
#pragma unroll
        for (int cc = 0; cc < CPQ; ++cc) pp[cc] = 0;
#pragma unroll
        for (int k = 0; k < K; ++k) {
            float bdm = INFINITY; int bim = 0x7FFFFFFF; int bc = -1;
#pragma unroll
            for (int cc = 0; cc < CPQ; ++cc) {
                float dd = pool_d[(ql * CPQ + cc) * K + pp[cc]];
                int   ii = pool_i[(ql * CPQ + cc) * K + pp[cc]];
                if (lex_less(dd, ii, bdm, bim)) { bdm = dd; bim = ii; bc = cc; }
            }
            fd[k] = bdm; fi[k] = bim;
#pragma unroll
            for (int cc = 0; cc < CPQ; ++cc) pp[cc] += (bc == cc);
        }

        if (KIND == 0) {
            const float* rb   = ((mode == 0) ? tgt : src) + bbase;
            const float* addf = flow + bbase;
            float cx = qx, cy = qy, cz = qz;
            if (mode == 1) {
                cx += addf[(size_t)oqi * 3 + 0];
                cy += addf[(size_t)oqi * 3 + 1];
                cz += addf[(size_t)oqi * 3 + 2];
            }
            float gx = 0.f, gy = 0.f, gz = 0.f;
#pragma unroll
            for (int k = 0; k < K; ++k) {
                int j = (fd[k] > RADIUS2) ? fi[0] : fi[k];
                float px = rb[(size_t)j * 3 + 0];
                float py = rb[(size_t)j * 3 + 1];
                float pz = rb[(size_t)j * 3 + 2];
                if (mode == 1) {
                    px += addf[(size_t)j * 3 + 0];
                    py += addf[(size_t)j * 3 + 1];
                    pz += addf[(size_t)j * 3 + 2];
                }
                gx += px - cx; gy += py - cy; gz += pz - cz;
            }
            float* outp = (mode == 0) ? outA : outB;
            outp[bbase + (size_t)oqi * 3 + 0] = gx / 9.0f;
            outp[bbase + (size_t)oqi * 3 + 1] = gy / 9.0f;
            outp[bbase + (size_t)oqi * 3 + 2] = gz / 9.0f;
        } else {
            float w[K]; float wsum = 0.f;
#pragma unroll
            for (int k = 0; k < K; ++k) { w[k] = 1.0f / (fd[k] + 1e-8f); wsum += w[k]; }
            float ix = 0.f, iy = 0.f, iz = 0.f;
#pragma unroll
            for (int k = 0; k < K; ++k) {
                int j = (fd[k] > RADIUS2) ? fi[0] : fi[k];
                float wn = w[k] / wsum;
                ix += wn * curv2[bbase + (size_t)j * 3 + 0];
                iy += wn * curv2[bbase + (size_t)j * 3 + 1];
                iz += wn * curv2[bbase + (size_t)j * 3 + 2];
            }
            float dx = ix - moved[bbase + (size_t)oqi * 3 + 0];
            float dy = iy - moved[bbase + (size_t)oqi * 3 + 1];
            float dz = iz - moved[bbase + (size_t)oqi * 3 + 2];
            float sqv = fmaf(dx, dx, fmaf(dy, dy, dz * dz));
            atomicAdd(&lsum, sqv);
        }
    }

    if (KIND == 1) {
        __syncthreads();
        if (tid == 0) atomicAdd(outA, lsum * invB);
    }
}

extern "C" void kernel_launch(void* const* d_in, const int* in_sizes, int n_in,
                              void* d_out, int out_size, void* d_ws, size_t ws_size,
                              hipStream_t stream) {
    const float* src  = (const float*)d_in[0];
    const float* tgt  = (const float*)d_in[1];
    const float* flow = (const float*)d_in[2];
    float* out = (float*)d_out;

    const int B = 2;
    const int N = in_sizes[0] / (B * 3);        // 8192

    float*  curv2  = (float*)d_ws;                         // B*N*3
    float*  moved  = curv2 + (size_t)B * N * 3;            // B*N*3
    float4* xyzw   = (float4*)(moved + (size_t)B * N * 3); // 6*N float4 (16B-aligned)
    int*    sidx   = (int*)(xyzw + (size_t)6 * N);         // 6*N
    int*    bstart = sidx + (size_t)6 * N;                 // 6*(NB+1)

    hipMemsetAsync(d_out, 0, sizeof(float), stream);

    sort_kernel<<<6, BLOCK, 0, stream>>>(src, tgt, flow, xyzw, sidx, bstart, N);

    // fused self-KNN curvatures: grid = 2 modes * B * N/32 = 1024 blocks
    knn_kernel<10, 8, 0, 96><<<2 * B * (N / 32), BLOCK, 0, stream>>>(
        src, tgt, flow, xyzw, sidx, bstart, nullptr, nullptr, curv2, moved, N, 0.f);

    // interp + loss: grid = B * N/32 = 512 blocks
    knn_kernel<5, 8, 1, 64><<<B * (N / 32), BLOCK, 0, stream>>>(
        src, tgt, flow, xyzw, sidx, bstart, curv2, moved, out, nullptr, N, 1.0f / B);
}